// Round 5
// baseline (192.031 us; speedup 1.0000x reference)
//
#include <hip/hip_runtime.h>
#include <hip/hip_bf16.h>

#define N 8192
#define D 256
#define NC 64
// sim = dot/0.5 = 2*dot; rows normalized -> fixed shift 2.0 replaces row-max
// (log-sum-exp shift invariance). Diagonal + positive-count handled in finalize
// (r3-verified math). P (masked dot sum) accumulated in sim's epilogue.

typedef __attribute__((ext_vector_type(8))) short bf16x8;
typedef __attribute__((ext_vector_type(4))) float f32x4;

#define K1 2.8853900817779268f   // 2*log2(e)
#define K2 (-2.8853900817779268f)

__device__ inline unsigned short f2bf(float x) {
    __hip_bfloat16 h = __float2bfloat16(x);
    return *reinterpret_cast<unsigned short*>(&h);
}

__device__ inline float fast_exp2(float t) {
#if __has_builtin(__builtin_amdgcn_exp2f)
    return __builtin_amdgcn_exp2f(t);
#else
    return __expf(t * 0.69314718056f);
#endif
}

// ---------------- kernel 1: fp32 -> bf16 convert + zero Z,P ----------------
__global__ void convert_kernel(const float4* __restrict__ E4, ushort4* __restrict__ Ebf4,
                               float* __restrict__ Z, float* __restrict__ P) {
    int i = blockIdx.x * blockDim.x + threadIdx.x;
    if (i < (N * D) / 4) {
        float4 v = E4[i];
        ushort4 o;
        o.x = f2bf(v.x); o.y = f2bf(v.y); o.z = f2bf(v.z); o.w = f2bf(v.w);
        Ebf4[i] = o;
    }
    if (i < N) { Z[i] = 0.0f; P[i] = 0.0f; }
}

// ---------------- kernel 2: streaming-tile sim, counted-vmcnt pipeline ----------------
// 1024 blocks x 512 thr (8 waves, 2x4 wave grid). Block: 256 rows x 256 cols.
// K=256 split into 8 chunks of BK=32. Per chunk: A slab 256x32 (16 KB) + B slab
// 256x32 (16 KB) = 32 KB, staged into one of FOUR rolling buffers (128 KB LDS)
// via global_load_lds(16B), linear dest + inverse-swizzled source (rule #21).
// Main loop per chunk: s_waitcnt vmcnt(4); s_barrier; stage(g+2); compute.
// vmcnt ledger: at chunk g, in-flight = stage(g) [issued g-2, oldest] + stage(g+1)
// [issued g-1]; vmcnt(4) guarantees stage(g)'s 4 loads landed, leaves g+1's flying.
// Buffer (g+2)%4 was last read at chunk g-2 -> all waves are 2 barriers past it.
__global__ __launch_bounds__(512, 2)
void sim_kernel(const __hip_bfloat16* __restrict__ Ebf,
                const int* __restrict__ labels,
                float* __restrict__ Z, float* __restrict__ P) {
    __shared__ unsigned char Bsh[4 * 32768];   // 128 KB

    const int tid  = threadIdx.x;
    const int lane = tid & 63;
    const int wid  = tid >> 6;        // 0..7
    const int wrow = wid >> 2;        // 0..1  (128-row half)
    const int wcol = wid & 3;         // 0..3  (64-col quarter)
    const int l15  = lane & 15;
    const int l4   = lane >> 4;       // 0..3
    const int p    = blockIdx.x >> 5;     // row panel (256 rows)
    const int q    = blockIdx.x & 31;     // col chunk (256 cols)
    const char* eb = (const char*)Ebf;

    // ---- staging: 4 gload_lds per thread per chunk (2 A slots + 2 B slots) ----
    // slot = j*512 + wid*64 + lane (j=0,1 -> A; same for B). rc = slot>>2 (row/col
    // 0..255), s = slot&3 (16B seg of the 64B k-row). Source seg = s ^ ((rc>>1)&3)
    // (r2/r4-verified zero-conflict swizzle); LDS dest linear.
    auto stage = [&](int g) {
        const unsigned bufb = (unsigned)(g & 3) * 32768u;
        const char* kbase = eb + (size_t)g * 64;   // chunk k-offset (32 elems)
#pragma unroll
        for (int j = 0; j < 4; ++j) {
            int slot = (j & 1) * 512 + wid * 64 + lane;
            int rc   = slot >> 2;
            int s    = slot & 3;
            int ss   = s ^ ((rc >> 1) & 3);
            int base = (j >= 2) ? (q * 256) : (p * 256);   // B cols : A rows
            unsigned dest = bufb + ((j >= 2) ? 16384u : 0u) + (unsigned)slot * 16u;
            const char* src = kbase + (size_t)(base + rc) * 512 + ss * 16;
            __builtin_amdgcn_global_load_lds(
                (const __attribute__((address_space(1))) void*)src,
                (__attribute__((address_space(3))) void*)(Bsh + dest), 16, 0, 0);
        }
    };

    // prologue: 2 chunks in flight
    stage(0);
    stage(1);

    // labels for this wave's output rows (C/D row = l4*4 + r) and cols
    int labP[8], labj[4];
#pragma unroll
    for (int rg = 0; rg < 8; ++rg) {
        int rr = p * 256 + wrow * 128 + rg * 16 + l4 * 4;
        labP[rg] = labels[rr] | (labels[rr + 1] << 8) |
                   (labels[rr + 2] << 16) | (labels[rr + 3] << 24);
    }
#pragma unroll
    for (int cg = 0; cg < 4; ++cg)
        labj[cg] = labels[q * 256 + wcol * 64 + cg * 16 + l15];

    // lane-only swizzled read offset (identical formula for A and B reads)
    const unsigned laneOff = (unsigned)(l15 * 64 + ((l4 ^ ((l15 >> 1) & 3)) << 4));

    f32x4 acc[8][4];
#pragma unroll
    for (int rg = 0; rg < 8; ++rg)
#pragma unroll
        for (int cg = 0; cg < 4; ++cg) acc[rg][cg] = (f32x4){0.f, 0.f, 0.f, 0.f};

    for (int g = 0; g < 8; ++g) {
        if (g < 7) { asm volatile("s_waitcnt vmcnt(4)" ::: "memory"); }
        else       { asm volatile("s_waitcnt vmcnt(0)" ::: "memory"); }
        __builtin_amdgcn_s_barrier();
        if (g + 2 < 8) stage(g + 2);

        const unsigned bufb = (unsigned)(g & 3) * 32768u;
        const unsigned ab = bufb + (unsigned)wrow * 8192u + laneOff;
        const unsigned bb = bufb + 16384u + (unsigned)wcol * 4096u + laneOff;

        bf16x8 af[8], bf[4];
#pragma unroll
        for (int rg = 0; rg < 8; ++rg)
            af[rg] = *reinterpret_cast<const bf16x8*>(Bsh + ab + rg * 1024);
#pragma unroll
        for (int cg = 0; cg < 4; ++cg)
            bf[cg] = *reinterpret_cast<const bf16x8*>(Bsh + bb + cg * 1024);

        __builtin_amdgcn_s_setprio(1);
#pragma unroll
        for (int rg = 0; rg < 8; ++rg)
#pragma unroll
            for (int cg = 0; cg < 4; ++cg)
                acc[rg][cg] = __builtin_amdgcn_mfma_f32_16x16x32_bf16(
                    af[rg], bf[cg], acc[rg][cg], 0, 0, 0);
        __builtin_amdgcn_s_setprio(0);
    }

    // ---- epilogue: Z = sum exp2(K1*dot+K2), P = sum of label-matched raw dots ----
#pragma unroll
    for (int rg = 0; rg < 8; ++rg)
#pragma unroll
        for (int r = 0; r < 4; ++r) {
            int li = (labP[rg] >> (r * 8)) & 255;
            float z = 0.0f, pp = 0.0f;
#pragma unroll
            for (int cg = 0; cg < 4; ++cg) {
                float dd = acc[rg][cg][r];
                z  += fast_exp2(__builtin_fmaf(dd, K1, K2));
                pp += (li == labj[cg]) ? dd : 0.0f;
            }
#pragma unroll
            for (int m = 1; m <= 8; m <<= 1) {
                z  += __shfl_xor(z, m, 64);
                pp += __shfl_xor(pp, m, 64);
            }
            if (l15 == 0) {
                int row = p * 256 + wrow * 128 + rg * 16 + l4 * 4 + r;
                atomicAdd(&Z[row], z);
                atomicAdd(&P[row], pp);
            }
        }
}

// ---------------- kernel 3: finalize (hist + per-row loss + reduce + divide) ----------------
__global__ __launch_bounds__(1024)
void finalize_kernel(const float* __restrict__ Z, const float* __restrict__ P,
                     const int* __restrict__ labels, float* __restrict__ out) {
    __shared__ int hist[NC];
    __shared__ float s0[1024], s1[1024];
    int t = threadIdx.x;
    if (t < NC) hist[t] = 0;
    __syncthreads();
    for (int i = t; i < N; i += 1024) atomicAdd(&hist[labels[i]], 1);
    __syncthreads();

    float num = 0.0f, den = 0.0f;
    for (int i = t; i < N; i += 1024) {
        float z = Z[i] - 1.0f;            // remove diag exp(s_ii-2) ~= 1
        float pv = 2.0f * (P[i] - 1.0f);  // scale raw dots by 1/T=2; remove diag dot ~= 1
        float c = (float)(hist[labels[i]] - 1);
        num += c * (2.0f + __logf(z)) - pv;
        den += c;
    }
    s0[t] = num; s1[t] = den;
    __syncthreads();
    for (int s = 512; s > 0; s >>= 1) {
        if (t < s) { s0[t] += s0[t + s]; s1[t] += s1[t + s]; }
        __syncthreads();
    }
    if (t == 0) out[0] = s0[0] / s1[0];
}

extern "C" void kernel_launch(void* const* d_in, const int* in_sizes, int n_in,
                              void* d_out, int out_size, void* d_ws, size_t ws_size,
                              hipStream_t stream) {
    const float* emb  = (const float*)d_in[0];
    const int* labels = (const int*)d_in[1];
    float* out = (float*)d_out;

    char* ws = (char*)d_ws;
    __hip_bfloat16* Ebf = (__hip_bfloat16*)ws;          // 4 MB
    float* Z = (float*)(ws + (size_t)N * D * 2);        // 32 KB
    float* P = Z + N;                                   // 32 KB

    convert_kernel<<<(N * D / 4 + 255) / 256, 256, 0, stream>>>(
        (const float4*)emb, (ushort4*)Ebf, Z, P);
    sim_kernel<<<1024, 512, 0, stream>>>(Ebf, labels, Z, P);
    finalize_kernel<<<1, 1024, 0, stream>>>(Z, P, labels, out);
}

// Round 6
// 114.234 us; speedup vs baseline: 1.6810x; 1.6810x over previous
//
#include <hip/hip_runtime.h>
#include <hip/hip_bf16.h>

#define N 8192
#define D 256
#define NC 64
#define NQ 16        // col chunks (512 cols each)
#define NT 16        // 32-col tiles per block
// sim = dot/0.5 = 2*dot; rows normalized -> fixed shift 2.0 replaces row-max
// (log-sum-exp shift invariance). Diagonal + positive-count handled in finalize
// (r3/r4-verified math). NO global atomics: per-col-chunk partial buffers.

typedef __attribute__((ext_vector_type(8))) short bf16x8;
typedef __attribute__((ext_vector_type(4))) float f32x4;

#define K1 2.8853900817779268f   // 2*log2(e)
#define K2 (-2.8853900817779268f)

__device__ inline unsigned short f2bf(float x) {
    __hip_bfloat16 h = __float2bfloat16(x);
    return *reinterpret_cast<unsigned short*>(&h);
}

__device__ inline float fast_exp2(float t) {
#if __has_builtin(__builtin_amdgcn_exp2f)
    return __builtin_amdgcn_exp2f(t);
#else
    return __expf(t * 0.69314718056f);
#endif
}

// ---------------- kernel 1: fp32 -> bf16 convert ----------------
__global__ void convert_kernel(const float4* __restrict__ E4, ushort4* __restrict__ Ebf4) {
    int i = blockIdx.x * blockDim.x + threadIdx.x;
    if (i < (N * D) / 4) {
        float4 v = E4[i];
        ushort4 o;
        o.x = f2bf(v.x); o.y = f2bf(v.y); o.z = f2bf(v.z); o.w = f2bf(v.w);
        Ebf4[i] = o;
    }
}

// ---------------- kernel 2: fused sim + exp-sum + masked dot-sum ----------------
// 512 blocks x 256 thr (4 waves), 2 blocks/CU, all co-resident. Block: rows
// [rp*256,+256) x cols [q*512,+512) as 16 tiles of 32 cols x full K=256.
// A-frags register-resident (128 VGPR, zero A ds_reads). B slab 16 KB/tile in
// 3 rolling LDS buffers (48 KB), staged via global_load_lds(16B): linear dest +
// inverse-swizzled source (rule #21; r3/r4-measured zero bank conflicts).
// Pipeline: depth-2 prefetch, ONE raw s_barrier/tile, counted vmcnt(4) (never 0
// until tail). Ledger: at tile t in-flight = stage(t) 4 oldest + stage(t+1) 4;
// vmcnt(4) => t landed, t+1 flying. stage(t+2) -> buf (t+2)%3, last read t-1,
// one barrier back => safe. Prologue __syncthreads drains A/label loads so the
// vmcnt ledger counts stages only (no other VMEM in the loop: labels from LDS).
__global__ __launch_bounds__(256, 2)
void sim_kernel(const __hip_bfloat16* __restrict__ Ebf,
                const int* __restrict__ labels,
                float* __restrict__ Zp, float* __restrict__ Pp) {
    __shared__ unsigned char Bsh[3 * 16384];   // 48 KB
    __shared__ int Lcol[512];

    const int tid  = threadIdx.x;
    const int lane = tid & 63;
    const int wid  = tid >> 6;        // 0..3
    const int l15  = lane & 15;
    const int l4   = lane >> 4;       // 0..3
    const int rpnl = blockIdx.x >> 4; // row panel 0..31
    const int q    = blockIdx.x & 15; // col chunk 0..15
    const char* eb = (const char*)Ebf;

    // block col labels -> LDS
    {
        int i0 = tid * 2;
        Lcol[i0]     = labels[q * 512 + i0];
        Lcol[i0 + 1] = labels[q * 512 + i0 + 1];
    }

    // A fragments: row = l15, k-seg = l4; 4 row-groups x 8 kg x 16B
    bf16x8 a[4][8];
#pragma unroll
    for (int rg = 0; rg < 4; ++rg) {
        int row = rpnl * 256 + wid * 64 + rg * 16 + l15;
        const char* ap = eb + (size_t)row * 512 + l4 * 16;
#pragma unroll
        for (int kg = 0; kg < 8; ++kg)
            a[rg][kg] = *reinterpret_cast<const bf16x8*>(ap + kg * 64);
    }

    // packed labels of this lane's 16 output rows (C/D row = l4*4 + r)
    int labP[4];
#pragma unroll
    for (int rg = 0; rg < 4; ++rg) {
        int rr = rpnl * 256 + wid * 64 + rg * 16 + l4 * 4;
        labP[rg] = labels[rr] | (labels[rr + 1] << 8) |
                   (labels[rr + 2] << 16) | (labels[rr + 3] << 24);
    }

    __syncthreads();   // drain A/label VMEM; publish Lcol -> clean vmcnt ledger

    // lane-only swizzled ds_read offset (r3/r4-verified zero-conflict)
    const unsigned laneSwz = (unsigned)(l15 * 64 + ((l4 ^ ((l15 >> 1) & 3)) << 4));

    auto stage = [&](int t, int buf) {
        const unsigned bufb = (unsigned)buf * 16384u;
#pragma unroll
        for (int m = 0; m < 4; ++m) {
            int c = wid * 4 + m;                 // 16 chunks of 1 KB
            int kg = c >> 1, colblk = c & 1;
            int colLocal = colblk * 16 + (lane >> 2);
            int seg = (lane & 3) ^ ((colLocal >> 1) & 3);   // inverse swizzle on src
            const char* src = eb + (size_t)(q * 512 + t * 32 + colLocal) * 512
                            + kg * 64 + seg * 16;
            __builtin_amdgcn_global_load_lds(
                (const __attribute__((address_space(1))) void*)src,
                (__attribute__((address_space(3))) void*)
                    (Bsh + bufb + kg * 2048u + colblk * 1024u),
                16, 0, 0);
        }
    };

    float zacc[4][4], pacc[4][4];
#pragma unroll
    for (int rg = 0; rg < 4; ++rg)
#pragma unroll
        for (int r = 0; r < 4; ++r) { zacc[rg][r] = 0.0f; pacc[rg][r] = 0.0f; }

    stage(0, 0);
    stage(1, 1);

    int bcur = 0;
    for (int t = 0; t < NT; ++t) {
        if (t < NT - 1) { asm volatile("s_waitcnt vmcnt(4)" ::: "memory"); }
        else            { asm volatile("s_waitcnt vmcnt(0)" ::: "memory"); }
        __builtin_amdgcn_s_barrier();
        if (t + 2 < NT) {
            int bs = bcur + 2; if (bs >= 3) bs -= 3;
            stage(t + 2, bs);
        }

        const unsigned bufb = (unsigned)bcur * 16384u;
        f32x4 acc[4][2];
#pragma unroll
        for (int rg = 0; rg < 4; ++rg) {
            acc[rg][0] = (f32x4){0.f, 0.f, 0.f, 0.f};
            acc[rg][1] = (f32x4){0.f, 0.f, 0.f, 0.f};
        }

        __builtin_amdgcn_s_setprio(1);
#pragma unroll
        for (int kg = 0; kg < 8; ++kg) {
            bf16x8 b0 = *reinterpret_cast<const bf16x8*>(Bsh + bufb + kg * 2048 + laneSwz);
            bf16x8 b1 = *reinterpret_cast<const bf16x8*>(Bsh + bufb + kg * 2048 + 1024 + laneSwz);
#pragma unroll
            for (int rg = 0; rg < 4; ++rg) {
                acc[rg][0] = __builtin_amdgcn_mfma_f32_16x16x32_bf16(a[rg][kg], b0, acc[rg][0], 0, 0, 0);
                acc[rg][1] = __builtin_amdgcn_mfma_f32_16x16x32_bf16(a[rg][kg], b1, acc[rg][1], 0, 0, 0);
            }
        }
        __builtin_amdgcn_s_setprio(0);

        // epilogue: Z += exp2(K1*dot+K2); P += label-matched raw dots
        int labj0 = Lcol[t * 32 + l15];
        int labj1 = Lcol[t * 32 + 16 + l15];
#pragma unroll
        for (int rg = 0; rg < 4; ++rg)
#pragma unroll
            for (int r = 0; r < 4; ++r) {
                int li = (labP[rg] >> (r * 8)) & 255;
                float d0 = acc[rg][0][r], d1 = acc[rg][1][r];
                zacc[rg][r] += fast_exp2(__builtin_fmaf(d0, K1, K2))
                             + fast_exp2(__builtin_fmaf(d1, K1, K2));
                pacc[rg][r] += ((li == labj0) ? d0 : 0.0f)
                             + ((li == labj1) ? d1 : 0.0f);
            }

        bcur += 1; if (bcur >= 3) bcur -= 3;
    }

    // 16-lane shfl reduce over cols, then plain (atomic-free) partial stores
#pragma unroll
    for (int rg = 0; rg < 4; ++rg)
#pragma unroll
        for (int r = 0; r < 4; ++r) {
            float z = zacc[rg][r], pw = pacc[rg][r];
#pragma unroll
            for (int m = 1; m <= 8; m <<= 1) {
                z  += __shfl_xor(z, m, 64);
                pw += __shfl_xor(pw, m, 64);
            }
            if (l15 == 0) {
                int row = rpnl * 256 + wid * 64 + rg * 16 + l4 * 4 + r;
                Zp[q * N + row] = z;
                Pp[q * N + row] = pw;
            }
        }
}

// ---------------- kernel 3: finalize (partial-sum + hist + loss) ----------------
__global__ __launch_bounds__(1024)
void finalize_kernel(const float* __restrict__ Zp, const float* __restrict__ Pp,
                     const int* __restrict__ labels, float* __restrict__ out) {
    __shared__ int hist[NC];
    __shared__ float s0[1024], s1[1024];
    const int t = threadIdx.x;
    if (t < NC) hist[t] = 0;
    __syncthreads();
    for (int i = t; i < N; i += 1024) atomicAdd(&hist[labels[i]], 1);
    __syncthreads();

    float num = 0.0f, den = 0.0f;
    for (int i = t; i < N; i += 1024) {
        float z = 0.0f, pv = 0.0f;
#pragma unroll
        for (int qq = 0; qq < NQ; ++qq) {
            z  += Zp[qq * N + i];
            pv += Pp[qq * N + i];
        }
        z -= 1.0f;                 // remove diag exp(s_ii-2) ~= 1
        pv = 2.0f * (pv - 1.0f);   // scale raw dots by 1/T=2; remove diag dot ~= 1
        float c = (float)(hist[labels[i]] - 1);
        num += c * (2.0f + __logf(z)) - pv;
        den += c;
    }
    s0[t] = num; s1[t] = den;
    __syncthreads();
    for (int s = 512; s > 0; s >>= 1) {
        if (t < s) { s0[t] += s0[t + s]; s1[t] += s1[t + s]; }
        __syncthreads();
    }
    if (t == 0) out[0] = s0[0] / s1[0];
}

extern "C" void kernel_launch(void* const* d_in, const int* in_sizes, int n_in,
                              void* d_out, int out_size, void* d_ws, size_t ws_size,
                              hipStream_t stream) {
    const float* emb  = (const float*)d_in[0];
    const int* labels = (const int*)d_in[1];
    float* out = (float*)d_out;

    char* ws = (char*)d_ws;
    __hip_bfloat16* Ebf = (__hip_bfloat16*)ws;               // 4 MB
    float* Zp = (float*)(ws + (size_t)N * D * 2);            // 16x8192 fp32 = 512 KB
    float* Pp = Zp + NQ * N;                                 // 512 KB

    convert_kernel<<<(N * D / 4 + 255) / 256, 256, 0, stream>>>(
        (const float4*)emb, (ushort4*)Ebf);
    sim_kernel<<<512, 256, 0, stream>>>(Ebf, labels, Zp, Pp);
    finalize_kernel<<<1, 1024, 0, stream>>>(Zp, Pp, labels, out);
}